// Round 11
// baseline (125.594 us; speedup 1.0000x reference)
//
#include <hip/hip_runtime.h>
#include <math.h>

#define NB 128   // batch
#define ND 1024  // embed dim
#define NS 14    // sum of K_range
#define NDH 128  // head dim

typedef float f32x4 __attribute__((ext_vector_type(4)));
typedef short bf16x8 __attribute__((ext_vector_type(8)));   // 8 bf16 in 4 VGPRs
typedef unsigned int u32x4 __attribute__((ext_vector_type(4)));

__device__ __forceinline__ unsigned short f2bf(float v) {   // RNE, finite inputs
  unsigned int u = __builtin_bit_cast(unsigned int, v);
  return (unsigned short)((u + 0x7FFFu + ((u >> 16) & 1u)) >> 16);
}
__device__ __forceinline__ float bf2f(unsigned short u) {
  return __builtin_bit_cast(float, (unsigned int)u << 16);
}

// 8 fp32 -> bf16x8 via v_cvt_pk_bf16_f32 (gfx950)
__device__ __forceinline__ bf16x8 pack_bv(float4 w0, float4 w1) {
  unsigned int u0, u1, u2, u3;
  asm("v_cvt_pk_bf16_f32 %0, %1, %2" : "=v"(u0) : "v"(w0.x), "v"(w0.y));
  asm("v_cvt_pk_bf16_f32 %0, %1, %2" : "=v"(u1) : "v"(w0.z), "v"(w0.w));
  asm("v_cvt_pk_bf16_f32 %0, %1, %2" : "=v"(u2) : "v"(w1.x), "v"(w1.y));
  asm("v_cvt_pk_bf16_f32 %0, %1, %2" : "=v"(u3) : "v"(w1.z), "v"(w1.w));
  u32x4 u = {u0, u1, u2, u3};
  return __builtin_bit_cast(bf16x8, u);
}

// s in [0,14) -> group g in [0,4), k within group
__device__ __forceinline__ void s_decomp(int s, int& g, int& k) {
  if (s < 2)      { g = 0; k = s; }
  else if (s < 5) { g = 1; k = s - 2; }
  else if (s < 9) { g = 2; k = s - 5; }
  else            { g = 3; k = s - 9; }
}
__device__ __forceinline__ const float* grp_ptr(int g, const float* p2, const float* p3,
                                                const float* p4, const float* p5) {
  return g == 0 ? p2 : g == 1 ? p3 : g == 2 ? p4 : p5;
}
__device__ __forceinline__ int grp_base(int g) { return g == 0 ? 0 : g == 1 ? 16 : g == 2 ? 40 : 72; }
__device__ __forceinline__ int grp_k(int g) { return g + 2; }

// ---------------- K1: fused LN (bid<112, frag layout out) + assign (bid>=112, 2-lane dist). 240 x 256 ----------------
// hbf2 elem index: c*114688 + kblk*3584 + m*512 + (q*16 + r16)*8 + e
__global__ __launch_bounds__(256) void k_ln_assign(
    const float* __restrict__ x,
    const float* __restrict__ p2, const float* __restrict__ p3,
    const float* __restrict__ p4, const float* __restrict__ p5,
    const float* __restrict__ ln_g, const float* __restrict__ ln_b,
    unsigned short* __restrict__ hbf2, float* __restrict__ pall,
    int* __restrict__ cls, int* __restrict__ rows_g, float* __restrict__ minv)
{
  int bid = blockIdx.x, t = threadIdx.x;
  __shared__ __align__(16) float xs[ND];
  float4* xs4 = (float4*)xs;
  if (bid < 112) {
    int r = bid;
    const float* pp; int idx;
    if (r < 16)      { pp = p2; idx = r; }
    else if (r < 40) { pp = p3; idx = r - 16; }
    else if (r < 72) { pp = p4; idx = r - 40; }
    else             { pp = p5; idx = r - 72; }
    const float4* row4 = (const float4*)(pp + (size_t)idx * ND);
    float4 v = row4[t];
    xs4[t] = v;
    float s1 = v.x + v.y + v.z + v.w;
    float s2 = v.x * v.x + v.y * v.y + v.z * v.z + v.w * v.w;
    __shared__ float ra[256], rb[256];
    ra[t] = s1; rb[t] = s2; __syncthreads();
    for (int o = 128; o > 0; o >>= 1) { if (t < o) { ra[t] += ra[t + o]; rb[t] += rb[t + o]; } __syncthreads(); }
    __shared__ float mu, rstd;
    if (t == 0) {
      float m = ra[0] * (1.f / 1024.f);
      float var = rb[0] * (1.f / 1024.f) - m * m;
      mu = m; rstd = rsqrtf(var + 1e-5f);
    }
    __syncthreads();
    ((float4*)(pall + (size_t)r * ND))[t] = xs4[t];
    float4 xv = xs4[t];
    float nx = (xv.x - mu) * rstd, ny = (xv.y - mu) * rstd,
          nz = (xv.z - mu) * rstd, nw = (xv.w - mu) * rstd;
    int d0 = t * 4;
    int m = r >> 4, rr = r & 15;
    int kblk = d0 >> 5, qq = (d0 >> 3) & 3, e0 = d0 & 7;   // e0 in {0,4}
    size_t fidx = (size_t)kblk * 3584 + m * 512 + (qq * 16 + rr) * 8 + e0;
#pragma unroll
    for (int c = 0; c < 8; ++c) {
      float4 g = ((const float4*)(ln_g + (size_t)c * ND))[t];
      float4 bb = ((const float4*)(ln_b + (size_t)c * ND))[t];
      ushort4 u;
      u.x = f2bf(nx * g.x + bb.x); u.y = f2bf(ny * g.y + bb.y);
      u.z = f2bf(nz * g.z + bb.z); u.w = f2bf(nw * g.w + bb.w);
      *(ushort4*)&hbf2[(size_t)c * 114688 + fidx] = u;
    }
  } else {
    int b = bid - 112;
    __shared__ float d2s[112];
    __shared__ int cls_s[4];
    const float4* xg4 = (const float4*)(x + (size_t)b * ND);
    xs4[t] = xg4[t];
    __syncthreads();
    int j = t >> 1, half = t & 1;          // 2 lanes per proto row
    if (j < 112) {
      const float* pp; int idx;
      if (j < 16)      { pp = p2; idx = j; }
      else if (j < 40) { pp = p3; idx = j - 16; }
      else if (j < 72) { pp = p4; idx = j - 40; }
      else             { pp = p5; idx = j - 72; }
      const float4* pr4 = (const float4*)(pp + (size_t)idx * ND);
      float acc = 0.f;
      int d0 = half * 128;
#pragma unroll 8
      for (int d = d0; d < d0 + 128; ++d) {
        float4 a = xs4[d], p = pr4[d];
        float dx = a.x - p.x, dy = a.y - p.y, dz = a.z - p.z, dw = a.w - p.w;
        acc += dx * dx + dy * dy + dz * dz + dw * dw;
      }
      acc += __shfl_xor(acc, 1, 2);
      if (half == 0) d2s[j] = acc;
    }
    __syncthreads();
    if (t < 4) {
      int base = grp_base(t), kg = grp_k(t), cnt = 8 * kg;
      float mv = d2s[base]; int mi = 0;
      for (int jj = 1; jj < cnt; ++jj) { float v = d2s[base + jj]; if (v < mv) { mv = v; mi = jj; } }
      int c = mi / kg;
      cls[b * 4 + t] = c; cls_s[t] = c;
      minv[b * 4 + t] = mv;
    }
    __syncthreads();
    if (t < NS) {
      int g, k; s_decomp(t, g, k);
      rows_g[b * NS + t] = grp_base(g) + cls_s[g] * grp_k(g) + k;
    }
  }
}

// ---------------- K2: fused prep (bid=0) + qkv GEMM (bid>=1, reg-dbuf, split-K=4). 1537 x 256 ----------------
__global__ __launch_bounds__(256, 4) void k_qkv_prep(
    const unsigned short* __restrict__ hbf2, const float* __restrict__ w_qkv,
    const float* __restrict__ b_qkv, unsigned short* __restrict__ qkv_bf,
    const int* __restrict__ cls, const float* __restrict__ minv,
    int* __restrict__ counts, int* __restrict__ ccnt, int* __restrict__ order,
    int* __restrict__ posof, int* __restrict__ chunkidx, int* __restrict__ chunk_c,
    int* __restrict__ chunk_lo, int* __restrict__ chunkN, float* __restrict__ scal)
{
  int bid = blockIdx.x, t = threadIdx.x;
  if (bid == 0) {
    __shared__ int cnt_s[32];
    __shared__ int cc_s[8];
    __shared__ float red[128];
    if (t < 32) cnt_s[t] = 0;
    if (t < 8) cc_s[t] = 0;
    if (t < 4) scal[t] = 0.f;
    __syncthreads();
    if (t < 128) {
      int c3;
#pragma unroll
      for (int g = 0; g < 4; ++g) {
        int c = cls[t * 4 + g];
        atomicAdd(&cnt_s[g * 8 + c], 1);
        if (g == 3) c3 = c;
      }
      int pos = atomicAdd(&cc_s[c3], 1);
      order[c3 * 128 + pos] = t;
      posof[t] = pos;
      red[t] = minv[t * 4 + 0] + minv[t * 4 + 1] + minv[t * 4 + 2] + minv[t * 4 + 3];
    }
    __syncthreads();
    for (int o = 64; o > 0; o >>= 1) { if (t < o) red[t] += red[t + o]; __syncthreads(); }
    if (t == 0) {
      scal[0] = red[0];
      int T = 0;
      for (int c = 0; c < 8; ++c) {
        chunkidx[c] = T;
        int nch = (cc_s[c] + 15) >> 4;
        for (int j = 0; j < nch; ++j) { chunk_c[T] = c; chunk_lo[T] = j * 16; ++T; }
      }
      chunkN[0] = T;
    }
    if (t < 32) counts[t] = cnt_s[t];
    if (t < 8) ccnt[t] = cc_s[t];
    return;
  }
  // ---- qkv: N=16 cols/block, 4 split-K waves, register double-buffered ----
  __shared__ __align__(16) float lred[3 * 7 * 256];   // 21.5 KB
  int qb = bid - 1;
  int c = qb / 192, xb = qb - c * 192;
  int lane = t & 63, ks = t >> 6;
  int r16 = lane & 15, q = lane >> 4;
  int col = xb * 16 + r16;
  const float* Wp = w_qkv + ((size_t)c * 3072 + col) * ND + ks * 256 + q * 8;
  const unsigned short* Hp = hbf2 + (size_t)c * 114688 + (size_t)(ks * 8) * 3584 + lane * 8;
  f32x4 acc[7] = {};
  float4 w0 = *(const float4*)(Wp);
  float4 w1 = *(const float4*)(Wp + 4);
  bf16x8 av[7];
#pragma unroll
  for (int m = 0; m < 7; ++m) av[m] = *(const bf16x8*)(Hp + m * 512);
#pragma unroll
  for (int i = 0; i < 8; ++i) {
    float4 nw0, nw1; bf16x8 nav[7];
    if (i < 7) {
      nw0 = *(const float4*)(Wp + (i + 1) * 32);
      nw1 = *(const float4*)(Wp + (i + 1) * 32 + 4);
#pragma unroll
      for (int m = 0; m < 7; ++m) nav[m] = *(const bf16x8*)(Hp + (size_t)(i + 1) * 3584 + m * 512);
    }
    bf16x8 bv = pack_bv(w0, w1);
#pragma unroll
    for (int m = 0; m < 7; ++m)
      acc[m] = __builtin_amdgcn_mfma_f32_16x16x32_bf16(av[m], bv, acc[m], 0, 0, 0);
    if (i < 7) {
      w0 = nw0; w1 = nw1;
#pragma unroll
      for (int m = 0; m < 7; ++m) av[m] = nav[m];
    }
  }
  if (ks) {
#pragma unroll
    for (int m = 0; m < 7; ++m)
      *(f32x4*)&lred[((ks - 1) * 7 + m) * 256 + lane * 4] = acc[m];
  }
  __syncthreads();
  if (ks == 0) {
    float bq = b_qkv[(size_t)c * 3072 + col];
#pragma unroll
    for (int m = 0; m < 7; ++m) {
      f32x4 a1 = *(const f32x4*)&lred[(0 * 7 + m) * 256 + lane * 4];
      f32x4 a2 = *(const f32x4*)&lred[(1 * 7 + m) * 256 + lane * 4];
      f32x4 a3 = *(const f32x4*)&lred[(2 * 7 + m) * 256 + lane * 4];
#pragma unroll
      for (int r = 0; r < 4; ++r) {
        int row = m * 16 + q * 4 + r;
        qkv_bf[((size_t)c * 112 + row) * 3072 + col] = f2bf(acc[m][r] + a1[r] + a2[r] + a3[r] + bq);
      }
    }
  }
}

// ---------------- K3: fused attention (bid<1024) + stats (bid>=1024). 1080 x 256 ----------------
__global__ __launch_bounds__(256) void k_attn_stats(
    const unsigned short* __restrict__ qkv_bf, const int* __restrict__ cls,
    const int* __restrict__ rows_g, const int* __restrict__ posof,
    const int* __restrict__ chunkidx, unsigned short* __restrict__ obf2,
    const float* __restrict__ p2, const float* __restrict__ p3,
    const float* __restrict__ p4, const float* __restrict__ p5,
    const int* __restrict__ counts, float* __restrict__ M, float* __restrict__ scal)
{
  int bid = blockIdx.x, t = threadIdx.x;
  if (bid < 1024) {
    __shared__ __align__(16) float qs[NS * NDH], ks2[NS * NDH], vs[NS * NDH];
    __shared__ float sc[NS * NS];
    __shared__ int rg[NS];
    int h = bid & 7, b = bid >> 3;
    if (t < NS) rg[t] = rows_g[b * NS + t];
    __syncthreads();
    int cp = cls[b * 4 + 3];
    int pos = posof[b];
    size_t gbase = (size_t)(chunkidx[cp] + (pos >> 4)) * 229376;
    int slot = pos & 15;
    const float scale = 0.08838834764831843f;  // 128^-0.5
    for (int i = t; i < NS * 32; i += 256) {   // 448 ushort4 loads per array
      int s = i >> 5, e4 = (i & 31) * 4;
      size_t base = ((size_t)cp * 112 + rg[s]) * 3072 + h * NDH + e4;
      ushort4 uq = *(const ushort4*)&qkv_bf[base];
      ushort4 uk = *(const ushort4*)&qkv_bf[base + 1024];
      ushort4 uv = *(const ushort4*)&qkv_bf[base + 2048];
      int o = s * NDH + e4;
      qs[o]     = bf2f(uq.x) * scale; qs[o + 1] = bf2f(uq.y) * scale;
      qs[o + 2] = bf2f(uq.z) * scale; qs[o + 3] = bf2f(uq.w) * scale;
      ks2[o]     = bf2f(uk.x); ks2[o + 1] = bf2f(uk.y);
      ks2[o + 2] = bf2f(uk.z); ks2[o + 3] = bf2f(uk.w);
      vs[o]     = bf2f(uv.x); vs[o + 1] = bf2f(uv.y);
      vs[o + 2] = bf2f(uv.z); vs[o + 3] = bf2f(uv.w);
    }
    __syncthreads();
    if (t < NS * NS) {
      int si = t / NS, sj = t - (t / NS) * NS;
      const float4* qa = (const float4*)&qs[si * NDH];
      const float4* kb = (const float4*)&ks2[sj * NDH];
      float acc = 0.f;
#pragma unroll 8
      for (int e4 = 0; e4 < 32; ++e4) {
        float4 a = qa[e4], k4 = kb[e4];
        acc += a.x * k4.x + a.y * k4.y + a.z * k4.z + a.w * k4.w;
      }
      sc[t] = acc;
    }
    __syncthreads();
    if (t < NS) {
      float mx = -1e30f;
      for (int j = 0; j < NS; ++j) mx = fmaxf(mx, sc[t * NS + j]);
      float e_[NS]; float sum = 0.f;
      for (int j = 0; j < NS; ++j) { float e = expf(sc[t * NS + j] - mx); e_[j] = e; sum += e; }
      float inv = 1.f / sum;
      for (int j = 0; j < NS; ++j) sc[t * NS + j] = e_[j] * inv;
    }
    __syncthreads();
    for (int i = t; i < NS * 32; i += 256) {   // 448 float4 outputs
      int s = i >> 5, e4 = i & 31;
      float4 a = {0.f, 0.f, 0.f, 0.f};
#pragma unroll
      for (int j = 0; j < NS; ++j) {
        float w = sc[s * NS + j];
        float4 v4 = ((const float4*)&vs[j * NDH])[e4];
        a.x += w * v4.x; a.y += w * v4.y; a.z += w * v4.z; a.w += w * v4.w;
      }
      int row = slot * 14 + s;                  // 0..223
      int m = row >> 4, r16 = row & 15;
      int d0 = h * NDH + e4 * 4;
      int kblk = d0 >> 5, qq = (d0 >> 3) & 3, e0 = d0 & 7;
      ushort4 u; u.x = f2bf(a.x); u.y = f2bf(a.y); u.z = f2bf(a.z); u.w = f2bf(a.w);
      *(ushort4*)&obf2[gbase + (size_t)kblk * 7168 + m * 512 + (qq * 16 + r16) * 8 + e0] = u;
    }
  } else {
    // ---- stats: std_loss partials + M matrix ----
    int idx = (bid - 1024) * 256 + t;           // 56*256 = 14336 = NS*ND
    int s = idx >> 10, d = idx & 1023;
    int g, k; s_decomp(s, g, k);
    const float* pp = grp_ptr(g, p2, p3, p4, p5);
    int kg = grp_k(g);
    float vc[8], nc[8];
    float sum = 0.f, sumsq = 0.f;
#pragma unroll
    for (int c = 0; c < 8; ++c) {
      float v = pp[((size_t)(c * kg + k)) * ND + d];
      float n = (float)counts[g * 8 + c];
      vc[c] = v; nc[c] = n;
      sum += n * v; sumsq += n * v * v;
    }
    float mean = sum * (1.f / 128.f);
    float var = (sumsq - 128.f * mean * mean) * (1.f / 127.f);
    float sd = sqrtf(var + 1e-4f);
#pragma unroll
    for (int c = 0; c < 8; ++c)
      M[((size_t)(s * 8 + c)) * ND + d] = sqrtf(nc[c] * (1.f / 1791.f)) * (vc[c] - mean);
    float part = fmaxf(1.f - sd, 0.f);
    __shared__ float red[256];
    red[t] = part; __syncthreads();
    for (int o = 128; o > 0; o >>= 1) { if (t < o) red[t] += red[t + o]; __syncthreads(); }
    if (t == 0) atomicAdd(&scal[1], red[0]);
  }
}

// ---------------- K4: fused proj (bid<2048, reg-dbuf) + gram (2048..2159) + diag (2160..2163). 2164 x 256 ----------------
__global__ __launch_bounds__(256, 4) void k_proj_gram(
    const unsigned short* __restrict__ obf2, const int* __restrict__ order,
    const int* __restrict__ ccnt, const int* __restrict__ chunk_c,
    const int* __restrict__ chunk_lo, const int* __restrict__ chunkN,
    const int* __restrict__ rows_g,
    const float* __restrict__ w_proj, const float* __restrict__ b_proj,
    const float* __restrict__ pall, float* __restrict__ att,
    const float* __restrict__ M, float* __restrict__ scal)
{
  int bid = blockIdx.x, t = threadIdx.x;
  if (bid < 2048) {
    int xb = bid & 63;
    int grh = bid >> 6;                      // 0..31
    int rh = grh & 1, g = grh >> 1;          // g in 0..15
    if (g >= chunkN[0]) return;
    __shared__ __align__(16) float lred[3 * 7 * 256];   // 21.5 KB
    __shared__ int sid_s[16];
    int c = chunk_c[g], lo = chunk_lo[g];
    int cnt = ccnt[c];
    int nb = cnt - lo; if (nb > 16) nb = 16;
    int lane = t & 63, ks = t >> 6;
    if (t < 16) sid_s[t] = order[c * 128 + lo + ((t < nb) ? t : nb - 1)];
    int r16 = lane & 15, q = lane >> 4;
    int col = xb * 16 + r16;
    const float* Wp = w_proj + ((size_t)c * ND + col) * ND + ks * 256 + q * 8;
    const unsigned short* Ap = obf2 + (size_t)g * 229376 + (size_t)(ks * 8) * 7168 + rh * 3584 + lane * 8;
    f32x4 acc[7] = {};
    float4 w0 = *(const float4*)(Wp);
    float4 w1 = *(const float4*)(Wp + 4);
    bf16x8 av[7];
#pragma unroll
    for (int m = 0; m < 7; ++m) av[m] = *(const bf16x8*)(Ap + m * 512);
#pragma unroll
    for (int i = 0; i < 8; ++i) {
      float4 nw0, nw1; bf16x8 nav[7];
      if (i < 7) {
        nw0 = *(const float4*)(Wp + (i + 1) * 32);
        nw1 = *(const float4*)(Wp + (i + 1) * 32 + 4);
#pragma unroll
        for (int m = 0; m < 7; ++m) nav[m] = *(const bf16x8*)(Ap + (size_t)(i + 1) * 7168 + m * 512);
      }
      bf16x8 bv = pack_bv(w0, w1);
#pragma unroll
      for (int m = 0; m < 7; ++m)
        acc[m] = __builtin_amdgcn_mfma_f32_16x16x32_bf16(av[m], bv, acc[m], 0, 0, 0);
      if (i < 7) {
        w0 = nw0; w1 = nw1;
#pragma unroll
        for (int m = 0; m < 7; ++m) av[m] = nav[m];
      }
    }
    if (ks) {
#pragma unroll
      for (int m = 0; m < 7; ++m)
        *(f32x4*)&lred[((ks - 1) * 7 + m) * 256 + lane * 4] = acc[m];
    }
    __syncthreads();
    if (ks == 0) {
      float bp = b_proj[(size_t)c * ND + col];
#pragma unroll
      for (int m = 0; m < 7; ++m) {
        f32x4 a1 = *(const f32x4*)&lred[(0 * 7 + m) * 256 + lane * 4];
        f32x4 a2 = *(const f32x4*)&lred[(1 * 7 + m) * 256 + lane * 4];
        f32x4 a3 = *(const f32x4*)&lred[(2 * 7 + m) * 256 + lane * 4];
#pragma unroll
        for (int r = 0; r < 4; ++r) {
          int row = rh * 112 + m * 16 + q * 4 + r;            // 0..223 within chunk
          int slot = row / 14, s = row - slot * 14;
          if (slot < nb) {
            int b = sid_s[slot];
            float res = pall[(size_t)rows_g[b * NS + s] * ND + col];
            att[((size_t)b * NS + s) * ND + col] = acc[m][r] + a1[r] + a2[r] + a3[r] + bp + res;
          }
        }
      }
    }
  } else if (bid < 2160) {
    // ---- gram row r: ||M M^T||_F^2 partial. 2 lanes per j-row ----
    int r = bid - 2048;
    __shared__ __align__(16) float mi[ND];
    __shared__ float red2[128];
    float4* mi4 = (float4*)mi;
    const float4* src4 = (const float4*)(M + (size_t)r * ND);
    mi4[t] = src4[t];
    if (t < 128) red2[t] = 0.f;
    __syncthreads();
    int j = t >> 1, half = t & 1;
    if (j < 112) {
      const float4* mj4 = (const float4*)(M + (size_t)j * ND);
      float acc = 0.f;
      int d0 = half * 128;
#pragma unroll 8
      for (int d = d0; d < d0 + 128; ++d) {
        float4 a = mi4[d], b = mj4[d];
        acc += a.x * b.x + a.y * b.y + a.z * b.z + a.w * b.w;
      }
      acc += __shfl_xor(acc, 1, 2);
      if (half == 0) red2[j] = acc * acc;
    }
    __syncthreads();
    for (int o = 64; o > 0; o >>= 1) { if (t < o) red2[t] += red2[t + o]; __syncthreads(); }
    if (t == 0) atomicAdd(&scal[2], red2[0]);
  } else {
    // ---- diag: sum_d (cov_dd)^2, 256 dims per block, 4 blocks ----
    int d = (bid - 2160) * 256 + t;
    float tsum = 0.f;
    for (int r = 0; r < 112; ++r) { float v = M[(size_t)r * ND + d]; tsum += v * v; }
    __shared__ float red3[256];
    red3[t] = tsum * tsum; __syncthreads();
    for (int o = 128; o > 0; o >>= 1) { if (t < o) red3[t] += red3[t + o]; __syncthreads(); }
    if (t == 0) atomicAdd(&scal[3], red3[0]);
  }
}

// ---------------- K5: single-pass normalize+pool+logits from LDS tile; write vcr ----------------
__global__ __launch_bounds__(256) void k_final(
    const float* __restrict__ att, const float* __restrict__ w_cls,
    const float* __restrict__ b_cls, const float* __restrict__ scal,
    float* __restrict__ out)
{
  int b = blockIdx.x, t = threadIdx.x;
  __shared__ __align__(16) float as[NS * ND];   // 56 KB
  __shared__ float wred[NS][4];
  __shared__ float inv[NS];
  __shared__ __align__(16) float pooled[ND];
  int lane = t & 63, w = t >> 6;
#pragma unroll
  for (int s = 0; s < NS; ++s) {
    float4 v = ((const float4*)(att + ((size_t)b * NS + s) * ND))[t];
    ((float4*)&as[s * ND])[t] = v;
    float p = v.x * v.x + v.y * v.y + v.z * v.z + v.w * v.w;
#pragma unroll
    for (int o = 32; o > 0; o >>= 1) p += __shfl_xor(p, o, 64);
    if (lane == 0) wred[s][w] = p;
  }
  __syncthreads();
  if (t < NS) {
    float s2 = wred[t][0] + wred[t][1] + wred[t][2] + wred[t][3];
    inv[t] = 1.f / fmaxf(sqrtf(s2), 1e-12f);
  }
  __syncthreads();
  float4 pa = {0.f, 0.f, 0.f, 0.f};
#pragma unroll
  for (int s = 0; s < NS; ++s) {
    float iv = inv[s];
    float4 v = ((const float4*)&as[s * ND])[t];
    pa.x += iv * v.x; pa.y += iv * v.y; pa.z += iv * v.z; pa.w += iv * v.w;
  }
  const float k14 = 1.f / 14.f;
  pa.x *= k14; pa.y *= k14; pa.z *= k14; pa.w *= k14;
  ((float4*)pooled)[t] = pa;
  __syncthreads();
  int c = t >> 5, l = t & 31;
  float acc = 0.f;
#pragma unroll
  for (int k = 0; k < 8; ++k) {
    int i4 = l + k * 32;
    float4 p4 = ((const float4*)pooled)[i4];
    float4 wc = ((const float4*)(w_cls + (size_t)c * ND))[i4];
    acc += p4.x * wc.x + p4.y * wc.y + p4.z * wc.z + p4.w * wc.w;
  }
  for (int o = 16; o > 0; o >>= 1) acc += __shfl_down(acc, o, 32);
  if (l == 0) out[b * 8 + c] = acc + b_cls[c];
  if (b == 0 && t == 0) {
    float repr = scal[0] * (1.f / (128.f * 4.f * 1024.f));
    float stdl = scal[1] * (1.f / 14336.f);
    float covl = (scal[2] - scal[3]) * (1.f / 1024.f);
    out[1024] = 25.f * repr + 25.f * stdl + covl;
  }
}

extern "C" void kernel_launch(void* const* d_in, const int* in_sizes, int n_in,
                              void* d_out, int out_size, void* d_ws, size_t ws_size,
                              hipStream_t stream) {
  const float* x      = (const float*)d_in[0];
  const float* p2     = (const float*)d_in[1];
  const float* p3     = (const float*)d_in[2];
  const float* p4     = (const float*)d_in[3];
  const float* p5     = (const float*)d_in[4];
  const float* ln_g   = (const float*)d_in[5];
  const float* ln_b   = (const float*)d_in[6];
  const float* w_qkv  = (const float*)d_in[7];
  const float* b_qkv  = (const float*)d_in[8];
  const float* w_proj = (const float*)d_in[9];
  const float* b_proj = (const float*)d_in[10];
  const float* w_cls  = (const float*)d_in[11];
  const float* b_cls  = (const float*)d_in[12];
  float* out = (float*)d_out;
  char* ws = (char*)d_ws;

  float* scal      = (float*)(ws + 0);         // [0]=repr [1]=std [2]=fro [3]=diagsq
  int*   counts    = (int*)(ws + 64);          // [4][8]
  int*   ccnt      = (int*)(ws + 192);         // [8]
  int*   cls       = (int*)(ws + 256);         // [128][4]
  int*   rows_g    = (int*)(ws + 2304);        // [128][14]
  int*   order     = (int*)(ws + 9472);        // [8][128]
  float* minv      = (float*)(ws + 13568);     // [128][4]
  int*   posof     = (int*)(ws + 15616);       // [128]
  int*   chunkidx  = (int*)(ws + 16128);       // [8]
  int*   chunk_c   = (int*)(ws + 16160);       // [16]
  int*   chunk_lo  = (int*)(ws + 16224);       // [16]
  int*   chunkN    = (int*)(ws + 16288);       // [1]
  float* pall      = (float*)(ws + 16384);     // 112*1024 f32           -> 475,136
  unsigned short* hbf2 = (unsigned short*)(ws + 475136);   // 8*114688 bf16 frag  -> 2,310,144
  unsigned short* qkvb = (unsigned short*)(ws + 2310144);  // 8*112*3072 bf16     -> 7,815,168
  unsigned short* obf2 = (unsigned short*)(ws + 7815168);  // 16*229376 bf16 frag -> 15,155,200
  float* att       = (float*)(ws + 15155200);  // 128*14*1024 f32        -> 22,495,232
  float* M         = (float*)(ws + 22495232);  // 112*1024 f32           -> 22,953,984

  k_ln_assign<<<240, 256, 0, stream>>>(x, p2, p3, p4, p5, ln_g, ln_b, hbf2, pall, cls, rows_g, minv);
  k_qkv_prep<<<1537, 256, 0, stream>>>(hbf2, w_qkv, b_qkv, qkvb, cls, minv,
                                       counts, ccnt, order, posof, chunkidx, chunk_c, chunk_lo, chunkN, scal);
  k_attn_stats<<<1080, 256, 0, stream>>>(qkvb, cls, rows_g, posof, chunkidx, obf2,
                                         p2, p3, p4, p5, counts, M, scal);
  k_proj_gram<<<2164, 256, 0, stream>>>(obf2, order, ccnt, chunk_c, chunk_lo, chunkN, rows_g,
                                        w_proj, b_proj, pall, att, M, scal);
  k_final<<<128, 256, 0, stream>>>(att, w_cls, b_cls, scal, out);
}

// Round 12
// 119.011 us; speedup vs baseline: 1.0553x; 1.0553x over previous
//
#include <hip/hip_runtime.h>
#include <math.h>

#define NB 128   // batch
#define ND 1024  // embed dim
#define NS 14    // sum of K_range
#define NDH 128  // head dim

typedef float f32x4 __attribute__((ext_vector_type(4)));
typedef short bf16x8 __attribute__((ext_vector_type(8)));   // 8 bf16 in 4 VGPRs
typedef unsigned int u32x4 __attribute__((ext_vector_type(4)));

__device__ __forceinline__ unsigned short f2bf(float v) {   // RNE, finite inputs
  unsigned int u = __builtin_bit_cast(unsigned int, v);
  return (unsigned short)((u + 0x7FFFu + ((u >> 16) & 1u)) >> 16);
}
__device__ __forceinline__ float bf2f(unsigned short u) {
  return __builtin_bit_cast(float, (unsigned int)u << 16);
}

// 8 fp32 -> bf16x8 via v_cvt_pk_bf16_f32 (gfx950)
__device__ __forceinline__ bf16x8 pack_bv(float4 w0, float4 w1) {
  unsigned int u0, u1, u2, u3;
  asm("v_cvt_pk_bf16_f32 %0, %1, %2" : "=v"(u0) : "v"(w0.x), "v"(w0.y));
  asm("v_cvt_pk_bf16_f32 %0, %1, %2" : "=v"(u1) : "v"(w0.z), "v"(w0.w));
  asm("v_cvt_pk_bf16_f32 %0, %1, %2" : "=v"(u2) : "v"(w1.x), "v"(w1.y));
  asm("v_cvt_pk_bf16_f32 %0, %1, %2" : "=v"(u3) : "v"(w1.z), "v"(w1.w));
  u32x4 u = {u0, u1, u2, u3};
  return __builtin_bit_cast(bf16x8, u);
}

// s in [0,14) -> group g in [0,4), k within group
__device__ __forceinline__ void s_decomp(int s, int& g, int& k) {
  if (s < 2)      { g = 0; k = s; }
  else if (s < 5) { g = 1; k = s - 2; }
  else if (s < 9) { g = 2; k = s - 5; }
  else            { g = 3; k = s - 9; }
}
__device__ __forceinline__ const float* grp_ptr(int g, const float* p2, const float* p3,
                                                const float* p4, const float* p5) {
  return g == 0 ? p2 : g == 1 ? p3 : g == 2 ? p4 : p5;
}
__device__ __forceinline__ int grp_base(int g) { return g == 0 ? 0 : g == 1 ? 16 : g == 2 ? 40 : 72; }
__device__ __forceinline__ int grp_k(int g) { return g + 2; }

// ---------------- K1: fused LN (bid<112, frag layout out) + assign (bid>=112, 2-lane dist). 240 x 256 ----------------
// hbf2 elem index: c*114688 + kblk*3584 + m*512 + (q*16 + r16)*8 + e
__global__ __launch_bounds__(256) void k_ln_assign(
    const float* __restrict__ x,
    const float* __restrict__ p2, const float* __restrict__ p3,
    const float* __restrict__ p4, const float* __restrict__ p5,
    const float* __restrict__ ln_g, const float* __restrict__ ln_b,
    unsigned short* __restrict__ hbf2, float* __restrict__ pall,
    int* __restrict__ cls, int* __restrict__ rows_g, float* __restrict__ minv)
{
  int bid = blockIdx.x, t = threadIdx.x;
  __shared__ __align__(16) float xs[ND];
  float4* xs4 = (float4*)xs;
  if (bid < 112) {
    int r = bid;
    const float* pp; int idx;
    if (r < 16)      { pp = p2; idx = r; }
    else if (r < 40) { pp = p3; idx = r - 16; }
    else if (r < 72) { pp = p4; idx = r - 40; }
    else             { pp = p5; idx = r - 72; }
    const float4* row4 = (const float4*)(pp + (size_t)idx * ND);
    float4 v = row4[t];
    xs4[t] = v;
    float s1 = v.x + v.y + v.z + v.w;
    float s2 = v.x * v.x + v.y * v.y + v.z * v.z + v.w * v.w;
    __shared__ float ra[256], rb[256];
    ra[t] = s1; rb[t] = s2; __syncthreads();
    for (int o = 128; o > 0; o >>= 1) { if (t < o) { ra[t] += ra[t + o]; rb[t] += rb[t + o]; } __syncthreads(); }
    __shared__ float mu, rstd;
    if (t == 0) {
      float m = ra[0] * (1.f / 1024.f);
      float var = rb[0] * (1.f / 1024.f) - m * m;
      mu = m; rstd = rsqrtf(var + 1e-5f);
    }
    __syncthreads();
    ((float4*)(pall + (size_t)r * ND))[t] = xs4[t];
    float4 xv = xs4[t];
    float nx = (xv.x - mu) * rstd, ny = (xv.y - mu) * rstd,
          nz = (xv.z - mu) * rstd, nw = (xv.w - mu) * rstd;
    int d0 = t * 4;
    int m = r >> 4, rr = r & 15;
    int kblk = d0 >> 5, qq = (d0 >> 3) & 3, e0 = d0 & 7;   // e0 in {0,4}
    size_t fidx = (size_t)kblk * 3584 + m * 512 + (qq * 16 + rr) * 8 + e0;
#pragma unroll
    for (int c = 0; c < 8; ++c) {
      float4 g = ((const float4*)(ln_g + (size_t)c * ND))[t];
      float4 bb = ((const float4*)(ln_b + (size_t)c * ND))[t];
      ushort4 u;
      u.x = f2bf(nx * g.x + bb.x); u.y = f2bf(ny * g.y + bb.y);
      u.z = f2bf(nz * g.z + bb.z); u.w = f2bf(nw * g.w + bb.w);
      *(ushort4*)&hbf2[(size_t)c * 114688 + fidx] = u;
    }
  } else {
    int b = bid - 112;
    __shared__ float d2s[112];
    __shared__ int cls_s[4];
    const float4* xg4 = (const float4*)(x + (size_t)b * ND);
    xs4[t] = xg4[t];
    __syncthreads();
    int j = t >> 1, half = t & 1;          // 2 lanes per proto row
    if (j < 112) {
      const float* pp; int idx;
      if (j < 16)      { pp = p2; idx = j; }
      else if (j < 40) { pp = p3; idx = j - 16; }
      else if (j < 72) { pp = p4; idx = j - 40; }
      else             { pp = p5; idx = j - 72; }
      const float4* pr4 = (const float4*)(pp + (size_t)idx * ND);
      float acc = 0.f;
      int d0 = half * 128;
#pragma unroll 8
      for (int d = d0; d < d0 + 128; ++d) {
        float4 a = xs4[d], p = pr4[d];
        float dx = a.x - p.x, dy = a.y - p.y, dz = a.z - p.z, dw = a.w - p.w;
        acc += dx * dx + dy * dy + dz * dz + dw * dw;
      }
      acc += __shfl_xor(acc, 1, 2);
      if (half == 0) d2s[j] = acc;
    }
    __syncthreads();
    if (t < 4) {
      int base = grp_base(t), kg = grp_k(t), cnt = 8 * kg;
      float mv = d2s[base]; int mi = 0;
      for (int jj = 1; jj < cnt; ++jj) { float v = d2s[base + jj]; if (v < mv) { mv = v; mi = jj; } }
      int c = mi / kg;
      cls[b * 4 + t] = c; cls_s[t] = c;
      minv[b * 4 + t] = mv;
    }
    __syncthreads();
    if (t < NS) {
      int g, k; s_decomp(t, g, k);
      rows_g[b * NS + t] = grp_base(g) + cls_s[g] * grp_k(g) + k;
    }
  }
}

// ---------------- K2: fused prep (bid=0) + qkv GEMM (bid>=1, 32 cols/wave, split-K=4). 769 x 256 ----------------
__global__ __launch_bounds__(256, 4) void k_qkv_prep(
    const unsigned short* __restrict__ hbf2, const float* __restrict__ w_qkv,
    const float* __restrict__ b_qkv, unsigned short* __restrict__ qkv_bf,
    const int* __restrict__ cls, const float* __restrict__ minv,
    int* __restrict__ counts, int* __restrict__ ccnt, int* __restrict__ order,
    int* __restrict__ posof, int* __restrict__ chunkidx, int* __restrict__ chunk_c,
    int* __restrict__ chunk_lo, int* __restrict__ chunkN, float* __restrict__ scal)
{
  int bid = blockIdx.x, t = threadIdx.x;
  if (bid == 0) {
    __shared__ int cnt_s[32];
    __shared__ int cc_s[8];
    __shared__ float red[128];
    if (t < 32) cnt_s[t] = 0;
    if (t < 8) cc_s[t] = 0;
    if (t < 4) scal[t] = 0.f;
    __syncthreads();
    if (t < 128) {
      int c3;
#pragma unroll
      for (int g = 0; g < 4; ++g) {
        int c = cls[t * 4 + g];
        atomicAdd(&cnt_s[g * 8 + c], 1);
        if (g == 3) c3 = c;
      }
      int pos = atomicAdd(&cc_s[c3], 1);
      order[c3 * 128 + pos] = t;
      posof[t] = pos;
      red[t] = minv[t * 4 + 0] + minv[t * 4 + 1] + minv[t * 4 + 2] + minv[t * 4 + 3];
    }
    __syncthreads();
    for (int o = 64; o > 0; o >>= 1) { if (t < o) red[t] += red[t + o]; __syncthreads(); }
    if (t == 0) {
      scal[0] = red[0];
      int T = 0;
      for (int c = 0; c < 8; ++c) {
        chunkidx[c] = T;
        int nch = (cc_s[c] + 15) >> 4;
        for (int j = 0; j < nch; ++j) { chunk_c[T] = c; chunk_lo[T] = j * 16; ++T; }
      }
      chunkN[0] = T;
    }
    if (t < 32) counts[t] = cnt_s[t];
    if (t < 8) ccnt[t] = cc_s[t];
    return;
  }
  // ---- qkv: 32 cols per wave (2 B-frags), 4 split-K waves, 14 MFMA + 11 loads per iter ----
  __shared__ __align__(16) float lred[3 * 14 * 256];   // 43 KB
  int qb = bid - 1;
  int c = qb / 96, xb = qb - c * 96;
  int lane = t & 63, ks = t >> 6;
  int r16 = lane & 15, q = lane >> 4;
  int col0 = xb * 32 + r16, col1 = col0 + 16;
  const float* Wp0 = w_qkv + ((size_t)c * 3072 + col0) * ND + ks * 256 + q * 8;
  const float* Wp1 = Wp0 + (size_t)16 * ND;
  const unsigned short* Hp = hbf2 + (size_t)c * 114688 + (size_t)(ks * 8) * 3584 + lane * 8;
  f32x4 acc0[7] = {}, acc1[7] = {};
#pragma unroll
  for (int i = 0; i < 8; ++i) {
    float4 w00 = *(const float4*)(Wp0 + i * 32);
    float4 w01 = *(const float4*)(Wp0 + i * 32 + 4);
    float4 w10 = *(const float4*)(Wp1 + i * 32);
    float4 w11 = *(const float4*)(Wp1 + i * 32 + 4);
    bf16x8 av[7];
#pragma unroll
    for (int m = 0; m < 7; ++m) av[m] = *(const bf16x8*)(Hp + (size_t)i * 3584 + m * 512);
    bf16x8 bv0 = pack_bv(w00, w01);
    bf16x8 bv1 = pack_bv(w10, w11);
#pragma unroll
    for (int m = 0; m < 7; ++m) {
      acc0[m] = __builtin_amdgcn_mfma_f32_16x16x32_bf16(av[m], bv0, acc0[m], 0, 0, 0);
      acc1[m] = __builtin_amdgcn_mfma_f32_16x16x32_bf16(av[m], bv1, acc1[m], 0, 0, 0);
    }
  }
  if (ks) {
#pragma unroll
    for (int m = 0; m < 7; ++m) {
      *(f32x4*)&lred[((ks - 1) * 14 + m) * 256 + lane * 4] = acc0[m];
      *(f32x4*)&lred[((ks - 1) * 14 + 7 + m) * 256 + lane * 4] = acc1[m];
    }
  }
  __syncthreads();
  if (ks == 0) {
    float bq0 = b_qkv[(size_t)c * 3072 + col0];
    float bq1 = b_qkv[(size_t)c * 3072 + col1];
#pragma unroll
    for (int m = 0; m < 7; ++m) {
      f32x4 s0 = acc0[m], s1 = acc1[m];
#pragma unroll
      for (int sk = 0; sk < 3; ++sk) {
        s0 += *(const f32x4*)&lred[(sk * 14 + m) * 256 + lane * 4];
        s1 += *(const f32x4*)&lred[(sk * 14 + 7 + m) * 256 + lane * 4];
      }
#pragma unroll
      for (int r = 0; r < 4; ++r) {
        int row = m * 16 + q * 4 + r;
        qkv_bf[((size_t)c * 112 + row) * 3072 + col0] = f2bf(s0[r] + bq0);
        qkv_bf[((size_t)c * 112 + row) * 3072 + col1] = f2bf(s1[r] + bq1);
      }
    }
  }
}

// ---------------- K3: fused attention (bid<1024) + stats (bid>=1024). 1080 x 256 ----------------
__global__ __launch_bounds__(256) void k_attn_stats(
    const unsigned short* __restrict__ qkv_bf, const int* __restrict__ cls,
    const int* __restrict__ rows_g, const int* __restrict__ posof,
    const int* __restrict__ chunkidx, unsigned short* __restrict__ obf2,
    const float* __restrict__ p2, const float* __restrict__ p3,
    const float* __restrict__ p4, const float* __restrict__ p5,
    const int* __restrict__ counts, float* __restrict__ M, float* __restrict__ scal)
{
  int bid = blockIdx.x, t = threadIdx.x;
  if (bid < 1024) {
    __shared__ __align__(16) float qs[NS * NDH], ks2[NS * NDH], vs[NS * NDH];
    __shared__ float sc[NS * NS];
    __shared__ int rg[NS];
    int h = bid & 7, b = bid >> 3;
    if (t < NS) rg[t] = rows_g[b * NS + t];
    __syncthreads();
    int cp = cls[b * 4 + 3];
    int pos = posof[b];
    size_t gbase = (size_t)(chunkidx[cp] + (pos >> 4)) * 229376;
    int slot = pos & 15;
    const float scale = 0.08838834764831843f;  // 128^-0.5
    for (int i = t; i < NS * 32; i += 256) {   // 448 ushort4 loads per array
      int s = i >> 5, e4 = (i & 31) * 4;
      size_t base = ((size_t)cp * 112 + rg[s]) * 3072 + h * NDH + e4;
      ushort4 uq = *(const ushort4*)&qkv_bf[base];
      ushort4 uk = *(const ushort4*)&qkv_bf[base + 1024];
      ushort4 uv = *(const ushort4*)&qkv_bf[base + 2048];
      int o = s * NDH + e4;
      qs[o]     = bf2f(uq.x) * scale; qs[o + 1] = bf2f(uq.y) * scale;
      qs[o + 2] = bf2f(uq.z) * scale; qs[o + 3] = bf2f(uq.w) * scale;
      ks2[o]     = bf2f(uk.x); ks2[o + 1] = bf2f(uk.y);
      ks2[o + 2] = bf2f(uk.z); ks2[o + 3] = bf2f(uk.w);
      vs[o]     = bf2f(uv.x); vs[o + 1] = bf2f(uv.y);
      vs[o + 2] = bf2f(uv.z); vs[o + 3] = bf2f(uv.w);
    }
    __syncthreads();
    if (t < NS * NS) {
      int si = t / NS, sj = t - (t / NS) * NS;
      const float4* qa = (const float4*)&qs[si * NDH];
      const float4* kb = (const float4*)&ks2[sj * NDH];
      float acc = 0.f;
#pragma unroll 8
      for (int e4 = 0; e4 < 32; ++e4) {
        float4 a = qa[e4], k4 = kb[e4];
        acc += a.x * k4.x + a.y * k4.y + a.z * k4.z + a.w * k4.w;
      }
      sc[t] = acc;
    }
    __syncthreads();
    if (t < NS) {
      float mx = -1e30f;
      for (int j = 0; j < NS; ++j) mx = fmaxf(mx, sc[t * NS + j]);
      float e_[NS]; float sum = 0.f;
      for (int j = 0; j < NS; ++j) { float e = expf(sc[t * NS + j] - mx); e_[j] = e; sum += e; }
      float inv = 1.f / sum;
      for (int j = 0; j < NS; ++j) sc[t * NS + j] = e_[j] * inv;
    }
    __syncthreads();
    for (int i = t; i < NS * 32; i += 256) {   // 448 float4 outputs
      int s = i >> 5, e4 = i & 31;
      float4 a = {0.f, 0.f, 0.f, 0.f};
#pragma unroll
      for (int j = 0; j < NS; ++j) {
        float w = sc[s * NS + j];
        float4 v4 = ((const float4*)&vs[j * NDH])[e4];
        a.x += w * v4.x; a.y += w * v4.y; a.z += w * v4.z; a.w += w * v4.w;
      }
      int row = slot * 14 + s;                  // 0..223
      int m = row >> 4, r16 = row & 15;
      int d0 = h * NDH + e4 * 4;
      int kblk = d0 >> 5, qq = (d0 >> 3) & 3, e0 = d0 & 7;
      ushort4 u; u.x = f2bf(a.x); u.y = f2bf(a.y); u.z = f2bf(a.z); u.w = f2bf(a.w);
      *(ushort4*)&obf2[gbase + (size_t)kblk * 7168 + m * 512 + (qq * 16 + r16) * 8 + e0] = u;
    }
  } else {
    // ---- stats: std_loss partials + M matrix ----
    int idx = (bid - 1024) * 256 + t;           // 56*256 = 14336 = NS*ND
    int s = idx >> 10, d = idx & 1023;
    int g, k; s_decomp(s, g, k);
    const float* pp = grp_ptr(g, p2, p3, p4, p5);
    int kg = grp_k(g);
    float vc[8], nc[8];
    float sum = 0.f, sumsq = 0.f;
#pragma unroll
    for (int c = 0; c < 8; ++c) {
      float v = pp[((size_t)(c * kg + k)) * ND + d];
      float n = (float)counts[g * 8 + c];
      vc[c] = v; nc[c] = n;
      sum += n * v; sumsq += n * v * v;
    }
    float mean = sum * (1.f / 128.f);
    float var = (sumsq - 128.f * mean * mean) * (1.f / 127.f);
    float sd = sqrtf(var + 1e-4f);
#pragma unroll
    for (int c = 0; c < 8; ++c)
      M[((size_t)(s * 8 + c)) * ND + d] = sqrtf(nc[c] * (1.f / 1791.f)) * (vc[c] - mean);
    float part = fmaxf(1.f - sd, 0.f);
    __shared__ float red[256];
    red[t] = part; __syncthreads();
    for (int o = 128; o > 0; o >>= 1) { if (t < o) red[t] += red[t + o]; __syncthreads(); }
    if (t == 0) atomicAdd(&scal[1], red[0]);
  }
}

// ---------------- K4: fused proj (bid<960, 512thr shared-W) + gram (960..1071) + diag (1072..1073). 1074 x 512 ----------------
__global__ __launch_bounds__(512) void k_proj_gram(
    const unsigned short* __restrict__ obf2, const int* __restrict__ order,
    const int* __restrict__ ccnt, const int* __restrict__ chunk_c,
    const int* __restrict__ chunk_lo, const int* __restrict__ chunkN,
    const int* __restrict__ rows_g,
    const float* __restrict__ w_proj, const float* __restrict__ b_proj,
    const float* __restrict__ pall, float* __restrict__ att,
    const float* __restrict__ M, float* __restrict__ scal)
{
  int bid = blockIdx.x, t = threadIdx.x;
  if (bid < 960) {
    int g = bid / 64, xb = bid - g * 64;
    if (g >= chunkN[0]) return;
    __shared__ __align__(16) float lred[3 * 2 * 7 * 256];   // 43 KB
    __shared__ int sid_s[16];
    int c = chunk_c[g], lo = chunk_lo[g];
    int cnt = ccnt[c];
    int nb = cnt - lo; if (nb > 16) nb = 16;
    int lane = t & 63, wid = t >> 6;
    int rh = wid & 1, ks = wid >> 1;                        // 2 row-halves x 4 k-splits
    if (t < 16) sid_s[t] = order[c * 128 + lo + ((t < nb) ? t : nb - 1)];
    int r16 = lane & 15, q = lane >> 4;
    int col = xb * 16 + r16;
    const float* Wp = w_proj + ((size_t)c * ND + col) * ND + ks * 256 + q * 8;
    const unsigned short* Ap = obf2 + (size_t)g * 229376 + (size_t)(ks * 8) * 7168 + rh * 3584 + lane * 8;
    f32x4 acc[7] = {};
#pragma unroll
    for (int i = 0; i < 8; ++i) {
      float4 w0 = *(const float4*)(Wp + i * 32);
      float4 w1 = *(const float4*)(Wp + i * 32 + 4);
      bf16x8 bv = pack_bv(w0, w1);
      const unsigned short* ak = Ap + (size_t)i * 7168;
#pragma unroll
      for (int m = 0; m < 7; ++m) {
        bf16x8 av = *(const bf16x8*)(ak + m * 512);
        acc[m] = __builtin_amdgcn_mfma_f32_16x16x32_bf16(av, bv, acc[m], 0, 0, 0);
      }
    }
    if (ks) {
#pragma unroll
      for (int m = 0; m < 7; ++m)
        *(f32x4*)&lred[(((ks - 1) * 2 + rh) * 7 + m) * 256 + lane * 4] = acc[m];
    }
    __syncthreads();
    if (ks == 0) {
      float bp = b_proj[(size_t)c * ND + col];
#pragma unroll
      for (int m = 0; m < 7; ++m) {
        f32x4 a1 = *(const f32x4*)&lred[((0 * 2 + rh) * 7 + m) * 256 + lane * 4];
        f32x4 a2 = *(const f32x4*)&lred[((1 * 2 + rh) * 7 + m) * 256 + lane * 4];
        f32x4 a3 = *(const f32x4*)&lred[((2 * 2 + rh) * 7 + m) * 256 + lane * 4];
#pragma unroll
        for (int r = 0; r < 4; ++r) {
          int row = rh * 112 + m * 16 + q * 4 + r;            // 0..223 within chunk
          int slot = row / 14, s = row - slot * 14;
          if (slot < nb) {
            int b = sid_s[slot];
            float res = pall[(size_t)rows_g[b * NS + s] * ND + col];
            att[((size_t)b * NS + s) * ND + col] = acc[m][r] + a1[r] + a2[r] + a3[r] + bp + res;
          }
        }
      }
    }
  } else if (bid < 1072) {
    // ---- gram row r: ||M M^T||_F^2 partial. 4 lanes per j-row ----
    int r = bid - 960;
    __shared__ __align__(16) float mi[ND];
    __shared__ float red2[128];
    float4* mi4 = (float4*)mi;
    const float4* src4 = (const float4*)(M + (size_t)r * ND);
    if (t < 256) mi4[t] = src4[t];
    if (t < 128) red2[t] = 0.f;
    __syncthreads();
    int j = t >> 2, qd = t & 3;
    float p = 0.f;
    if (j < 112) {
      const float4* mj4 = (const float4*)(M + (size_t)j * ND);
      float acc = 0.f;
#pragma unroll 8
      for (int d = qd * 64; d < qd * 64 + 64; ++d) {
        float4 a = mi4[d], b = mj4[d];
        acc += a.x * b.x + a.y * b.y + a.z * b.z + a.w * b.w;
      }
      acc += __shfl_xor(acc, 1, 4);
      acc += __shfl_xor(acc, 2, 4);
      p = acc * acc;
    }
    if (qd == 0 && j < 112) red2[j] = p;
    __syncthreads();
    for (int o = 64; o > 0; o >>= 1) { if (t < o) red2[t] += red2[t + o]; __syncthreads(); }
    if (t == 0) atomicAdd(&scal[2], red2[0]);
  } else {
    // ---- diag: sum_d (cov_dd)^2, 512 dims per block ----
    int d = (bid - 1072) * 512 + t;
    float tsum = 0.f;
    for (int r = 0; r < 112; ++r) { float v = M[(size_t)r * ND + d]; tsum += v * v; }
    __shared__ float red3[512];
    red3[t] = tsum * tsum; __syncthreads();
    for (int o = 256; o > 0; o >>= 1) { if (t < o) red3[t] += red3[t + o]; __syncthreads(); }
    if (t == 0) atomicAdd(&scal[3], red3[0]);
  }
}

// ---------------- K5: single-pass normalize+pool+logits from LDS tile; write vcr ----------------
__global__ __launch_bounds__(256) void k_final(
    const float* __restrict__ att, const float* __restrict__ w_cls,
    const float* __restrict__ b_cls, const float* __restrict__ scal,
    float* __restrict__ out)
{
  int b = blockIdx.x, t = threadIdx.x;
  __shared__ __align__(16) float as[NS * ND];   // 56 KB
  __shared__ float wred[NS][4];
  __shared__ float inv[NS];
  __shared__ __align__(16) float pooled[ND];
  int lane = t & 63, w = t >> 6;
#pragma unroll
  for (int s = 0; s < NS; ++s) {
    float4 v = ((const float4*)(att + ((size_t)b * NS + s) * ND))[t];
    ((float4*)&as[s * ND])[t] = v;
    float p = v.x * v.x + v.y * v.y + v.z * v.z + v.w * v.w;
#pragma unroll
    for (int o = 32; o > 0; o >>= 1) p += __shfl_xor(p, o, 64);
    if (lane == 0) wred[s][w] = p;
  }
  __syncthreads();
  if (t < NS) {
    float s2 = wred[t][0] + wred[t][1] + wred[t][2] + wred[t][3];
    inv[t] = 1.f / fmaxf(sqrtf(s2), 1e-12f);
  }
  __syncthreads();
  float4 pa = {0.f, 0.f, 0.f, 0.f};
#pragma unroll
  for (int s = 0; s < NS; ++s) {
    float iv = inv[s];
    float4 v = ((const float4*)&as[s * ND])[t];
    pa.x += iv * v.x; pa.y += iv * v.y; pa.z += iv * v.z; pa.w += iv * v.w;
  }
  const float k14 = 1.f / 14.f;
  pa.x *= k14; pa.y *= k14; pa.z *= k14; pa.w *= k14;
  ((float4*)pooled)[t] = pa;
  __syncthreads();
  int c = t >> 5, l = t & 31;
  float acc = 0.f;
#pragma unroll
  for (int k = 0; k < 8; ++k) {
    int i4 = l + k * 32;
    float4 p4 = ((const float4*)pooled)[i4];
    float4 wc = ((const float4*)(w_cls + (size_t)c * ND))[i4];
    acc += p4.x * wc.x + p4.y * wc.y + p4.z * wc.z + p4.w * wc.w;
  }
  for (int o = 16; o > 0; o >>= 1) acc += __shfl_down(acc, o, 32);
  if (l == 0) out[b * 8 + c] = acc + b_cls[c];
  if (b == 0 && t == 0) {
    float repr = scal[0] * (1.f / (128.f * 4.f * 1024.f));
    float stdl = scal[1] * (1.f / 14336.f);
    float covl = (scal[2] - scal[3]) * (1.f / 1024.f);
    out[1024] = 25.f * repr + 25.f * stdl + covl;
  }
}

extern "C" void kernel_launch(void* const* d_in, const int* in_sizes, int n_in,
                              void* d_out, int out_size, void* d_ws, size_t ws_size,
                              hipStream_t stream) {
  const float* x      = (const float*)d_in[0];
  const float* p2     = (const float*)d_in[1];
  const float* p3     = (const float*)d_in[2];
  const float* p4     = (const float*)d_in[3];
  const float* p5     = (const float*)d_in[4];
  const float* ln_g   = (const float*)d_in[5];
  const float* ln_b   = (const float*)d_in[6];
  const float* w_qkv  = (const float*)d_in[7];
  const float* b_qkv  = (const float*)d_in[8];
  const float* w_proj = (const float*)d_in[9];
  const float* b_proj = (const float*)d_in[10];
  const float* w_cls  = (const float*)d_in[11];
  const float* b_cls  = (const float*)d_in[12];
  float* out = (float*)d_out;
  char* ws = (char*)d_ws;

  float* scal      = (float*)(ws + 0);         // [0]=repr [1]=std [2]=fro [3]=diagsq
  int*   counts    = (int*)(ws + 64);          // [4][8]
  int*   ccnt      = (int*)(ws + 192);         // [8]
  int*   cls       = (int*)(ws + 256);         // [128][4]
  int*   rows_g    = (int*)(ws + 2304);        // [128][14]
  int*   order     = (int*)(ws + 9472);        // [8][128]
  float* minv      = (float*)(ws + 13568);     // [128][4]
  int*   posof     = (int*)(ws + 15616);       // [128]
  int*   chunkidx  = (int*)(ws + 16128);       // [8]
  int*   chunk_c   = (int*)(ws + 16160);       // [16]
  int*   chunk_lo  = (int*)(ws + 16224);       // [16]
  int*   chunkN    = (int*)(ws + 16288);       // [1]
  float* pall      = (float*)(ws + 16384);     // 112*1024 f32           -> 475,136
  unsigned short* hbf2 = (unsigned short*)(ws + 475136);   // 8*114688 bf16 frag  -> 2,310,144
  unsigned short* qkvb = (unsigned short*)(ws + 2310144);  // 8*112*3072 bf16     -> 7,815,168
  unsigned short* obf2 = (unsigned short*)(ws + 7815168);  // 16*229376 bf16 frag -> 15,155,200
  float* att       = (float*)(ws + 15155200);  // 128*14*1024 f32        -> 22,495,232
  float* M         = (float*)(ws + 22495232);  // 112*1024 f32           -> 22,953,984

  k_ln_assign<<<240, 256, 0, stream>>>(x, p2, p3, p4, p5, ln_g, ln_b, hbf2, pall, cls, rows_g, minv);
  k_qkv_prep<<<769, 256, 0, stream>>>(hbf2, w_qkv, b_qkv, qkvb, cls, minv,
                                      counts, ccnt, order, posof, chunkidx, chunk_c, chunk_lo, chunkN, scal);
  k_attn_stats<<<1080, 256, 0, stream>>>(qkvb, cls, rows_g, posof, chunkidx, obf2,
                                         p2, p3, p4, p5, counts, M, scal);
  k_proj_gram<<<1074, 512, 0, stream>>>(obf2, order, ccnt, chunk_c, chunk_lo, chunkN, rows_g,
                                        w_proj, b_proj, pall, att, M, scal);
  k_final<<<128, 256, 0, stream>>>(att, w_cls, b_cls, scal, out);
}